// Round 6
// baseline (6221.757 us; speedup 1.0000x reference)
//
#include <hip/hip_runtime.h>
#include <math.h>

// ---- problem dims ----
#define B_    32
#define D_    384
#define DEPTH 24
#define DI    768
#define DS    16
#define DCONV 4
#define DTR   24
#define L_    197
#define LPAD  208      // 13*16, padded token count for barrier-free scan
#define NCLS  1000
#define NTOK  (B_*L_)   // 6304
#define MPAD  6400      // padded row count for GEMM A buffers
#define NCOMB 896       // composite dt|B|C GEMM width (768 dt + 16 B + 16 C + 96 pad)

typedef __bf16 bf16;
typedef __bf16 bf16x2 __attribute__((ext_vector_type(2)));
typedef __bf16 bf16x8 __attribute__((ext_vector_type(8)));
typedef float  floatx4 __attribute__((ext_vector_type(4)));

#define INW_E  (1536*384)
#define OUTW_E (384*768)
#define PW_E   (384*768)
#define HW_E   (1024*384)

__device__ __forceinline__ float sigmoidf_(float x){ return 1.f/(1.f+__expf(-x)); }

// ---------------- all-weights fp32 -> bf16 conversion (once per call) ----------------
__global__ void wconv_all_kernel(const float* __restrict__ in_w, const float* __restrict__ out_w,
                                 const float* __restrict__ patch_w, const float* __restrict__ head_w,
                                 bf16* __restrict__ w_in_b, bf16* __restrict__ w_out_b,
                                 bf16* __restrict__ pw_b, bf16* __restrict__ hw_b)
{
    long idx = (long)blockIdx.x*256 + threadIdx.x;
    if (idx < (long)DEPTH*INW_E) { w_in_b[idx] = (bf16)in_w[idx]; return; }
    idx -= (long)DEPTH*INW_E;
    if (idx < (long)DEPTH*OUTW_E) { w_out_b[idx] = (bf16)out_w[idx]; return; }
    idx -= (long)DEPTH*OUTW_E;
    if (idx < PW_E) { pw_b[idx] = (bf16)patch_w[idx]; return; }
    idx -= PW_E;
    if (idx < HW_E) hw_b[idx] = (idx < (long)NCLS*384) ? (bf16)head_w[idx] : (bf16)0.f;
}

// ---------------- per-layer composite weight: rows 0..767 = dtw@xp_w[0:24];
// rows 768..799 = xp_w[24..55] (B then C); rows 800..895 = 0.  grid 896 ----------------
__global__ void wcomb_kernel(const float* __restrict__ dtw, const float* __restrict__ xpw,
                             bf16* __restrict__ wc)
{
    __shared__ float sw[24];
    const int o = blockIdx.x;
    if (o < 768) {
        if (threadIdx.x < 24) sw[threadIdx.x] = dtw[(long)o*DTR + threadIdx.x];
        __syncthreads();
        for (int i = threadIdx.x; i < DI; i += 256) {
            float acc = 0.f;
            #pragma unroll
            for (int r = 0; r < 24; ++r) acc += sw[r]*xpw[r*DI + i];
            wc[(long)o*DI + i] = (bf16)acc;
        }
    } else if (o < 800) {
        const float* src = xpw + (long)(o - 768 + 24)*DI;
        for (int i = threadIdx.x; i < DI; i += 256) wc[(long)o*DI + i] = (bf16)src[i];
    } else {
        for (int i = threadIdx.x; i < DI; i += 256) wc[(long)o*DI + i] = (bf16)0.f;
    }
}

// ---------------- im2col: x[B,3,224,224] -> patches[b*197+1+pi, 768] bf16 ----------------
__global__ void im2col_kernel(const float* __restrict__ x, bf16* __restrict__ patches)
{
    const long idx = (long)blockIdx.x*256 + threadIdx.x;
    if (idx >= (long)B_*196*768) return;
    const int k = idx % 768;
    const int prow = idx / 768;
    const int b = prow / 196, pi = prow % 196;
    const int ph = pi / 14, pw = pi % 14;
    const int c = k >> 8, rem = k & 255, ii = rem >> 4, jj = rem & 15;
    patches[((long)(b*L_ + 1 + pi))*768 + k] =
        (bf16)x[(((long)b*3 + c)*224 + ph*16 + ii)*224 + pw*16 + jj];
}

// ---------------- tok = feat + pb + pos ; cls row = cls + pos ----------------
__global__ void add_pos_kernel(float* __restrict__ tok, const float* __restrict__ pb,
                               const float* __restrict__ pos, const float* __restrict__ cls)
{
    const int idx = blockIdx.x*256 + threadIdx.x;
    if (idx >= NTOK*D_) return;
    const int dd = idx % D_;
    const int row = idx / D_;
    const int p = row % L_;
    if (p == 0) tok[idx] = cls[dd] + pos[dd];
    else        tok[idx] += pb[dd] + pos[p*D_ + dd];
}

// ---------------- layernorm over last dim 384, one wave per row ----------------
template<typename OUT_T>
__global__ void ln_kernel(const float* __restrict__ x, const float* __restrict__ w,
                          const float* __restrict__ b, OUT_T* __restrict__ out,
                          int rows, int xstride, int ostride)
{
    const int row = blockIdx.x*blockDim.y + threadIdx.y;
    if (row >= rows) return;
    const int lane = threadIdx.x;
    const float* xr = x + (long)row*xstride;
    float v[6]; float s = 0.f;
    #pragma unroll
    for (int i = 0; i < 6; ++i) { v[i] = xr[lane + 64*i]; s += v[i]; }
    #pragma unroll
    for (int o = 32; o; o >>= 1) s += __shfl_xor(s, o, 64);
    const float mu = s * (1.f/384.f);
    float var = 0.f;
    #pragma unroll
    for (int i = 0; i < 6; ++i) { float d = v[i]-mu; var += d*d; }
    #pragma unroll
    for (int o = 32; o; o >>= 1) var += __shfl_xor(var, o, 64);
    const float rstd = rsqrtf(var*(1.f/384.f) + 1e-5f);
    OUT_T* orow = out + (long)row*ostride;
    #pragma unroll
    for (int i = 0; i < 6; ++i) { int c = lane + 64*i; orow[c] = (OUT_T)((v[i]-mu)*rstd*w[c] + b[c]); }
}

// ---------------- bf16 MFMA GEMM:  C[m,n] (+)= A[m,:K] . B[n,:K]  (B stored [N][K]) ----------------
// BMx128 tile, BK=32, 256 threads.  BM=128: 4 waves 2x2 of 64x64.  BM=64: 4 waves of 64x32.
template<int BM, int ACC, typename CT>
__global__ __launch_bounds__(256)
void gemm_bf16_kernel(const bf16* __restrict__ A, const bf16* __restrict__ B,
                      CT* __restrict__ C, int M, int N, int K)
{
    constexpr int ASLABS = BM/16;
    constexpr int NJ = (BM == 128) ? 4 : 2;
    __shared__ bf16 As[BM*32];
    __shared__ bf16 Bs[128*32];
    const int tid  = threadIdx.x;
    const int wave = tid >> 6, lane = tid & 63;
    const int bm = blockIdx.x*BM, bn = blockIdx.y*128;
    const int wm = (BM == 128) ? (wave>>1)*64 : 0;
    const int wn = (BM == 128) ? (wave&1)*64 : wave*32;
    floatx4 acc[4][NJ];
    #pragma unroll
    for (int i=0;i<4;++i)
        #pragma unroll
        for (int j=0;j<NJ;++j) acc[i][j] = (floatx4){0.f,0.f,0.f,0.f};

    const int lrow = lane >> 2;          // 0..15 (row within 16-row slab)
    const int lcol = (lane & 3) * 8;     // bf16 element col offset
    const int am = lane & 15, ak = (lane>>4)*8;

    for (int k0 = 0; k0 < K; k0 += 32) {
        #pragma unroll
        for (int s = wave; s < ASLABS + 8; s += 4) {
            if (s < ASLABS) {
                const bf16* ga = A + (long)(bm + s*16 + lrow)*K + k0 + lcol;
                __builtin_amdgcn_global_load_lds(
                    (const __attribute__((address_space(1))) void*)ga,
                    (__attribute__((address_space(3))) void*)(As + s*512), 16, 0, 0);
            } else {
                const int s2 = s - ASLABS;
                const bf16* gb = B + (long)(bn + s2*16 + lrow)*K + k0 + lcol;
                __builtin_amdgcn_global_load_lds(
                    (const __attribute__((address_space(1))) void*)gb,
                    (__attribute__((address_space(3))) void*)(Bs + s2*512), 16, 0, 0);
            }
        }
        __syncthreads();
        bf16x8 af[4], bff[NJ];
        #pragma unroll
        for (int i=0;i<4;++i) af[i]  = *(const bf16x8*)(As + (wm + i*16 + am)*32 + ak);
        #pragma unroll
        for (int j=0;j<NJ;++j) bff[j] = *(const bf16x8*)(Bs + (wn + j*16 + am)*32 + ak);
        #pragma unroll
        for (int i=0;i<4;++i)
            #pragma unroll
            for (int j=0;j<NJ;++j)
                acc[i][j] = __builtin_amdgcn_mfma_f32_16x16x32_bf16(af[i], bff[j], acc[i][j], 0, 0, 0);
        __syncthreads();
    }
    // epilogue: C/D layout col=lane&15, row=(lane>>4)*4+reg
    const int rbase = bm + wm + (lane>>4)*4;
    const int cbase = bn + wn + (lane & 15);
    #pragma unroll
    for (int i = 0; i < 4; ++i) {
        #pragma unroll
        for (int r = 0; r < 4; ++r) {
            const int row = rbase + i*16 + r;
            if (row >= M) continue;
            #pragma unroll
            for (int j = 0; j < NJ; ++j) {
                const long idx = (long)row*N + cbase + j*16;
                if (ACC) C[idx] += acc[i][j][r];
                else     C[idx]  = (CT)acc[i][j][r];
            }
        }
    }
}

// ---------------- causal depthwise conv1d (DCONV=4) + bias + silu -> bf16, x2 vectorized ----------------
__global__ void conv_silu_kernel(const bf16* __restrict__ xz, const float* __restrict__ cw,
                                 const float* __restrict__ cb, bf16* __restrict__ out)
{
    const int idx = blockIdx.x*256 + threadIdx.x;      // over NTOK*DI/2
    if (idx >= NTOK*(DI/2)) return;
    const int dp = idx % (DI/2);
    const int bl = idx / (DI/2);
    const int l  = bl % L_;
    const int di = dp*2;
    const long rowbase = (long)(bl - l)*(2*DI) + di;
    const float4 wa = *(const float4*)(cw + di*4);
    const float4 wb = *(const float4*)(cw + di*4 + 4);
    float a0 = cb[di], a1 = cb[di+1];
    #pragma unroll
    for (int k = 0; k < 4; ++k) {
        const int lt = l - 3 + k;
        if (lt >= 0) {
            const bf16x2 xv = *(const bf16x2*)(xz + rowbase + (long)lt*(2*DI));
            const float w0 = (k==0)?wa.x:(k==1)?wa.y:(k==2)?wa.z:wa.w;
            const float w1 = (k==0)?wb.x:(k==1)?wb.y:(k==2)?wb.z:wb.w;
            a0 += w0 * (float)xv[0];
            a1 += w1 * (float)xv[1];
        }
    }
    bf16x2 r;
    r[0] = (bf16)(a0 * sigmoidf_(a0));
    r[1] = (bf16)(a1 * sigmoidf_(a1));
    *(bf16x2*)(out + (long)bl*DI + di) = r;
}

// ---------------- barrier-free selective scan + D-skip + gate -> y bf16 ----------------
// block 256 = 16 di x 16 s. grid (DI/16, B_). Whole 197-token slice staged in LDS once
// (52 KB), ONE barrier, then the token loop runs register/LDS-only with no syncs.
__global__ __launch_bounds__(256)
void scan_kernel(const bf16* __restrict__ xbc, const bf16* __restrict__ comb,
                 const bf16* __restrict__ xz, const float* __restrict__ A_log,
                 const float* __restrict__ Dp, const float* __restrict__ dtb,
                 bf16* __restrict__ y)
{
    const int tid  = threadIdx.x;
    const int w    = tid >> 6, lane = tid & 63;
    const int s    = lane & 15;        // state index / write-token index
    const int dlq  = lane >> 4;        // 0..3
    const int dl   = w*4 + dlq;        // block-local di 0..15
    const int di0  = blockIdx.x*16;
    const int di   = di0 + dl;
    const int b    = blockIdx.y;

    const float A_s = -__expf(A_log[di*DS + s]);
    const float Dv  = Dp[di];

    __shared__ float2 sh_dtdx[LPAD*16];  // (dt, dt*x)     26.0 KB
    __shared__ bf16x2 sh_bc[LPAD*16];    // (B, C)         13.0 KB
    __shared__ bf16x2 sh_xz[LPAD*16];    // (x, z)         13.0 KB

    const long base = (long)b*L_;
    const int e = tid & 15;              // staging column (constant across idx loop)
    const float bias = dtb[di0 + e];
    for (int idx = tid; idx < LPAD*16; idx += 256) {
        const int t = idx >> 4;
        float2 dtdx = {0.f, 0.f};
        bf16x2 bc;  bc[0] = (bf16)0.f; bc[1] = (bf16)0.f;
        bf16x2 xzv; xzv[0] = (bf16)0.f; xzv[1] = (bf16)0.f;
        if (t < L_) {
            const long row = base + t;
            const float xv = (float)xbc[row*DI + di0 + e];
            const float zv = (float)xz[row*(2*DI) + DI + di0 + e];
            const float dr = (float)comb[row*NCOMB + di0 + e] + bias;
            const float dtv = (dr > 20.f) ? dr : log1pf(__expf(dr));
            dtdx.x = dtv; dtdx.y = dtv*xv;
            bc[0] = comb[row*NCOMB + 768 + e];
            bc[1] = comb[row*NCOMB + 784 + e];
            xzv[0] = (bf16)xv; xzv[1] = (bf16)zv;
        }
        sh_dtdx[idx] = dtdx;
        sh_bc[idx]   = bc;
        sh_xz[idx]   = xzv;
    }
    __syncthreads();

    float h = 0.f;
    for (int c = 0; c < LPAD/16; ++c) {
        float v[16];
        #pragma unroll
        for (int t = 0; t < 16; ++t) {
            const int gt = c*16 + t;
            const float2 dd = sh_dtdx[gt*16 + dl];   // broadcast (4 addrs/wave)
            const bf16x2 bc = sh_bc[gt*16 + s];      // 16 addrs, conflict-free
            const float a = __expf(dd.x * A_s);
            h = fmaf(a, h, dd.y * (float)bc[0]);
            v[t] = h * (float)bc[1];
        }
        // reduce-scatter over the 16 s-lanes: lane s ends with total for token c*16+s
        #pragma unroll
        for (int m = 8; m >= 1; m >>= 1) {
            const bool hi = (s & m) != 0;
            #pragma unroll
            for (int i = 0; i < m; ++i) {
                const float keep = hi ? v[i + m] : v[i];
                const float send = hi ? v[i] : v[i + m];
                v[i] = keep + __shfl_xor(send, m, 64);
            }
        }
        const int gt = c*16 + s;
        if (gt < L_) {
            const bf16x2 xzv = sh_xz[gt*16 + dl];
            const float xv = (float)xzv[0], z = (float)xzv[1];
            y[(base + gt)*DI + di] = (bf16)((v[0] + Dv*xv) * z * sigmoidf_(z));
        }
    }
}

// ---------------- head bias + copy from padded GEMM output ----------------
__global__ void head_bias_kernel(const float* __restrict__ chead, const float* __restrict__ hb,
                                 float* __restrict__ out)
{
    const int idx = blockIdx.x*256 + threadIdx.x;
    if (idx >= B_*NCLS) return;
    const int n = idx % NCLS, b = idx / NCLS;
    out[idx] = chead[(long)b*1024 + n] + hb[n];
}

extern "C" void kernel_launch(void* const* d_in, const int* in_sizes, int n_in,
                              void* d_out, int out_size, void* d_ws, size_t ws_size,
                              hipStream_t stream)
{
    const float* x       = (const float*)d_in[0];
    const float* patch_w = (const float*)d_in[1];
    const float* patch_b = (const float*)d_in[2];
    const float* cls_tok = (const float*)d_in[3];
    const float* pos_emb = (const float*)d_in[4];
    const float* ln_w    = (const float*)d_in[5];
    const float* ln_b    = (const float*)d_in[6];
    const float* in_w    = (const float*)d_in[7];
    const float* conv_w  = (const float*)d_in[8];
    const float* conv_b  = (const float*)d_in[9];
    const float* xp_w    = (const float*)d_in[10];
    const float* dt_w    = (const float*)d_in[11];
    const float* dt_b    = (const float*)d_in[12];
    const float* A_log   = (const float*)d_in[13];
    const float* D_par   = (const float*)d_in[14];
    const float* out_w   = (const float*)d_in[15];
    const float* normf_w = (const float*)d_in[16];
    const float* normf_b = (const float*)d_in[17];
    const float* head_w  = (const float*)d_in[18];
    const float* head_b  = (const float*)d_in[19];
    float* out = (float*)d_out;

    // workspace layout (~111 MB)
    char* p = (char*)d_ws;
    float* tok    = (float*)p;  p += (long)NTOK*D_*4;          // 9.68 MB
    bf16*  xz_b   = (bf16*)p;   p += (long)MPAD*2*DI*2;        // 19.66 MB
    bf16*  xbc_b  = (bf16*)p;   p += (long)MPAD*DI*2;          // 9.83 MB
    bf16*  y_b    = (bf16*)p;   p += (long)MPAD*DI*2;          // 9.83 MB
    bf16*  comb_b = (bf16*)p;   p += (long)MPAD*NCOMB*2;       // 11.47 MB (aliases im2col patches)
    bf16*  xnorm_b= (bf16*)p;   p += (long)MPAD*D_*2;          // 4.92 MB
    bf16*  ln0_b  = (bf16*)p;   p += (long)64*D_*2;
    float* chead  = (float*)p;  p += (long)64*1024*4;
    bf16*  wcomb_b= (bf16*)p;   p += (long)NCOMB*DI*2;         // 1.38 MB
    bf16*  w_in_b = (bf16*)p;   p += (long)DEPTH*INW_E*2;      // 28.3 MB
    bf16*  w_out_b= (bf16*)p;   p += (long)DEPTH*OUTW_E*2;     // 14.2 MB
    bf16*  pw_b   = (bf16*)p;   p += (long)PW_E*2;             // 0.59 MB
    bf16*  hw_b   = (bf16*)p;   p += (long)HW_E*2;             // 0.79 MB
    bf16*  patches = comb_b;    // pre-loop only

    const long WCONV_E = (long)DEPTH*(INW_E + OUTW_E) + PW_E + HW_E;
    wconv_all_kernel<<<dim3((WCONV_E + 255)/256), 256, 0, stream>>>(
        in_w, out_w, patch_w, head_w, w_in_b, w_out_b, pw_b, hw_b);

    im2col_kernel<<<dim3(((long)B_*196*768 + 255)/256), 256, 0, stream>>>(x, patches);
    gemm_bf16_kernel<64,0,float><<<dim3(100, 3), 256, 0, stream>>>(
        patches, pw_b, tok, NTOK, D_, 768);
    add_pos_kernel<<<dim3((NTOK*D_ + 255)/256), 256, 0, stream>>>(tok, patch_b, pos_emb, cls_tok);

    for (int layer = 0; layer < DEPTH; ++layer) {
        ln_kernel<bf16><<<dim3(NTOK/4), dim3(64,4), 0, stream>>>(
            tok, ln_w + layer*D_, ln_b + layer*D_, xnorm_b, NTOK, D_, D_);
        gemm_bf16_kernel<128,0,bf16><<<dim3(50, 12), 256, 0, stream>>>(
            xnorm_b, w_in_b + (long)layer*INW_E, xz_b, NTOK, 2*DI, D_);
        conv_silu_kernel<<<dim3((NTOK*(DI/2) + 255)/256), 256, 0, stream>>>(
            xz_b, conv_w + layer*DI*DCONV, conv_b + layer*DI, xbc_b);
        wcomb_kernel<<<dim3(NCOMB), 256, 0, stream>>>(
            dt_w + (long)layer*DI*DTR, xp_w + (long)layer*56*768, wcomb_b);
        gemm_bf16_kernel<128,0,bf16><<<dim3(50, 7), 256, 0, stream>>>(
            xbc_b, wcomb_b, comb_b, NTOK, NCOMB, DI);
        scan_kernel<<<dim3(DI/16, B_), 256, 0, stream>>>(
            xbc_b, comb_b, xz_b, A_log + layer*DI*DS, D_par + layer*DI,
            dt_b + layer*DI, y_b);
        gemm_bf16_kernel<64,1,float><<<dim3(100, 3), 256, 0, stream>>>(
            y_b, w_out_b + (long)layer*OUTW_E, tok, NTOK, D_, DI);
    }

    ln_kernel<bf16><<<dim3(8), dim3(64,4), 0, stream>>>(tok, normf_w, normf_b, ln0_b, B_, L_*D_, D_);
    gemm_bf16_kernel<64,0,float><<<dim3(1, 8), 256, 0, stream>>>(
        ln0_b, hw_b, chead, 64, 1024, D_);
    head_bias_kernel<<<dim3((B_*NCLS + 255)/256), 256, 0, stream>>>(chead, head_b, out);
}

// Round 7
// 3352.457 us; speedup vs baseline: 1.8559x; 1.8559x over previous
//
#include <hip/hip_runtime.h>
#include <math.h>

// ---- problem dims ----
#define B_    32
#define D_    384
#define DEPTH 24
#define DI    768
#define DS    16
#define DCONV 4
#define DTR   24
#define L_    197
#define LPAD  208      // 13*16, padded token count for barrier-free scan
#define NCLS  1000
#define NTOK  (B_*L_)   // 6304
#define MPAD  6400      // padded row count for GEMM A buffers
#define NCOMB 896       // composite dt|B|C GEMM width (768 dt + 16 B + 16 C + 96 pad)

typedef __bf16 bf16;
typedef __bf16 bf16x2 __attribute__((ext_vector_type(2)));
typedef __bf16 bf16x4 __attribute__((ext_vector_type(4)));
typedef __bf16 bf16x8 __attribute__((ext_vector_type(8)));
typedef float  floatx4 __attribute__((ext_vector_type(4)));

#define INW_E  (1536*384)
#define OUTW_E (384*768)
#define PW_E   (384*768)
#define HW_E   (1024*384)

__device__ __forceinline__ float sigmoidf_(float x){ return 1.f/(1.f+__expf(-x)); }

// DPP-based lane exchange within 16-lane rows (keeps the LDS pipe free)
template<int CTRL>
__device__ __forceinline__ float dppf_(float x){
    return __int_as_float(__builtin_amdgcn_update_dpp(0, __float_as_int(x), CTRL, 0xF, 0xF, true));
}
template<int M>
__device__ __forceinline__ float sxor_(float x){
    if constexpr (M==1)      return dppf_<0xB1>(x);               // quad_perm [1,0,3,2]
    else if constexpr (M==2) return dppf_<0x4E>(x);               // quad_perm [2,3,0,1]
    else if constexpr (M==4) return dppf_<0x1B>(dppf_<0x141>(x)); // xor7 then xor3 = xor4
    else                     return dppf_<0x128>(x);              // row_ror:8 = xor8 (row=16)
}
template<int M>
__device__ __forceinline__ void rlevel_(float* v, const int s){
    const bool hi = (s & M) != 0;
    #pragma unroll
    for (int i = 0; i < M; ++i) {
        const float keep = hi ? v[i+M] : v[i];
        const float send = hi ? v[i] : v[i+M];
        v[i] = keep + sxor_<M>(send);
    }
}

// ---------------- all-weights fp32 -> bf16 conversion (once per call) ----------------
__global__ void wconv_all_kernel(const float* __restrict__ in_w, const float* __restrict__ out_w,
                                 const float* __restrict__ patch_w, const float* __restrict__ head_w,
                                 bf16* __restrict__ w_in_b, bf16* __restrict__ w_out_b,
                                 bf16* __restrict__ pw_b, bf16* __restrict__ hw_b)
{
    long idx = (long)blockIdx.x*256 + threadIdx.x;
    if (idx < (long)DEPTH*INW_E) { w_in_b[idx] = (bf16)in_w[idx]; return; }
    idx -= (long)DEPTH*INW_E;
    if (idx < (long)DEPTH*OUTW_E) { w_out_b[idx] = (bf16)out_w[idx]; return; }
    idx -= (long)DEPTH*OUTW_E;
    if (idx < PW_E) { pw_b[idx] = (bf16)patch_w[idx]; return; }
    idx -= PW_E;
    if (idx < HW_E) hw_b[idx] = (idx < (long)NCLS*384) ? (bf16)head_w[idx] : (bf16)0.f;
}

// ---------------- per-layer composite weight: rows 0..767 = dtw@xp_w[0:24];
// rows 768..799 = xp_w[24..55] (B then C); rows 800..895 = 0.  grid 896 ----------------
__global__ void wcomb_kernel(const float* __restrict__ dtw, const float* __restrict__ xpw,
                             bf16* __restrict__ wc)
{
    __shared__ float sw[24];
    const int o = blockIdx.x;
    if (o < 768) {
        if (threadIdx.x < 24) sw[threadIdx.x] = dtw[(long)o*DTR + threadIdx.x];
        __syncthreads();
        for (int i = threadIdx.x; i < DI; i += 256) {
            float acc = 0.f;
            #pragma unroll
            for (int r = 0; r < 24; ++r) acc += sw[r]*xpw[r*DI + i];
            wc[(long)o*DI + i] = (bf16)acc;
        }
    } else if (o < 800) {
        const float* src = xpw + (long)(o - 768 + 24)*DI;
        for (int i = threadIdx.x; i < DI; i += 256) wc[(long)o*DI + i] = (bf16)src[i];
    } else {
        for (int i = threadIdx.x; i < DI; i += 256) wc[(long)o*DI + i] = (bf16)0.f;
    }
}

// ---------------- im2col: x[B,3,224,224] -> patches[b*197+1+pi, 768] bf16 ----------------
__global__ void im2col_kernel(const float* __restrict__ x, bf16* __restrict__ patches)
{
    const long idx = (long)blockIdx.x*256 + threadIdx.x;
    if (idx >= (long)B_*196*768) return;
    const int k = idx % 768;
    const int prow = idx / 768;
    const int b = prow / 196, pi = prow % 196;
    const int ph = pi / 14, pw = pi % 14;
    const int c = k >> 8, rem = k & 255, ii = rem >> 4, jj = rem & 15;
    patches[((long)(b*L_ + 1 + pi))*768 + k] =
        (bf16)x[(((long)b*3 + c)*224 + ph*16 + ii)*224 + pw*16 + jj];
}

// ---------------- tok = feat + pb + pos ; cls row = cls + pos ----------------
__global__ void add_pos_kernel(float* __restrict__ tok, const float* __restrict__ pb,
                               const float* __restrict__ pos, const float* __restrict__ cls)
{
    const int idx = blockIdx.x*256 + threadIdx.x;
    if (idx >= NTOK*D_) return;
    const int dd = idx % D_;
    const int row = idx / D_;
    const int p = row % L_;
    if (p == 0) tok[idx] = cls[dd] + pos[dd];
    else        tok[idx] += pb[dd] + pos[p*D_ + dd];
}

// ---------------- layernorm over last dim 384, one wave per row ----------------
template<typename OUT_T>
__global__ void ln_kernel(const float* __restrict__ x, const float* __restrict__ w,
                          const float* __restrict__ b, OUT_T* __restrict__ out,
                          int rows, int xstride, int ostride)
{
    const int row = blockIdx.x*blockDim.y + threadIdx.y;
    if (row >= rows) return;
    const int lane = threadIdx.x;
    const float* xr = x + (long)row*xstride;
    float v[6]; float s = 0.f;
    #pragma unroll
    for (int i = 0; i < 6; ++i) { v[i] = xr[lane + 64*i]; s += v[i]; }
    #pragma unroll
    for (int o = 32; o; o >>= 1) s += __shfl_xor(s, o, 64);
    const float mu = s * (1.f/384.f);
    float var = 0.f;
    #pragma unroll
    for (int i = 0; i < 6; ++i) { float d = v[i]-mu; var += d*d; }
    #pragma unroll
    for (int o = 32; o; o >>= 1) var += __shfl_xor(var, o, 64);
    const float rstd = rsqrtf(var*(1.f/384.f) + 1e-5f);
    OUT_T* orow = out + (long)row*ostride;
    #pragma unroll
    for (int i = 0; i < 6; ++i) { int c = lane + 64*i; orow[c] = (OUT_T)((v[i]-mu)*rstd*w[c] + b[c]); }
}

// ---------------- bf16 MFMA GEMM:  C[m,n] (+)= A[m,:K] . B[n,:K]  (B stored [N][K]) ----------------
template<int BM, int ACC, typename CT>
__global__ __launch_bounds__(256)
void gemm_bf16_kernel(const bf16* __restrict__ A, const bf16* __restrict__ B,
                      CT* __restrict__ C, int M, int N, int K)
{
    constexpr int ASLABS = BM/16;
    constexpr int NJ = (BM == 128) ? 4 : 2;
    __shared__ bf16 As[BM*32];
    __shared__ bf16 Bs[128*32];
    const int tid  = threadIdx.x;
    const int wave = tid >> 6, lane = tid & 63;
    const int bm = blockIdx.x*BM, bn = blockIdx.y*128;
    const int wm = (BM == 128) ? (wave>>1)*64 : 0;
    const int wn = (BM == 128) ? (wave&1)*64 : wave*32;
    floatx4 acc[4][NJ];
    #pragma unroll
    for (int i=0;i<4;++i)
        #pragma unroll
        for (int j=0;j<NJ;++j) acc[i][j] = (floatx4){0.f,0.f,0.f,0.f};

    const int lrow = lane >> 2;
    const int lcol = (lane & 3) * 8;
    const int am = lane & 15, ak = (lane>>4)*8;

    for (int k0 = 0; k0 < K; k0 += 32) {
        #pragma unroll
        for (int s = wave; s < ASLABS + 8; s += 4) {
            if (s < ASLABS) {
                const bf16* ga = A + (long)(bm + s*16 + lrow)*K + k0 + lcol;
                __builtin_amdgcn_global_load_lds(
                    (const __attribute__((address_space(1))) void*)ga,
                    (__attribute__((address_space(3))) void*)(As + s*512), 16, 0, 0);
            } else {
                const int s2 = s - ASLABS;
                const bf16* gb = B + (long)(bn + s2*16 + lrow)*K + k0 + lcol;
                __builtin_amdgcn_global_load_lds(
                    (const __attribute__((address_space(1))) void*)gb,
                    (__attribute__((address_space(3))) void*)(Bs + s2*512), 16, 0, 0);
            }
        }
        __syncthreads();
        bf16x8 af[4], bff[NJ];
        #pragma unroll
        for (int i=0;i<4;++i) af[i]  = *(const bf16x8*)(As + (wm + i*16 + am)*32 + ak);
        #pragma unroll
        for (int j=0;j<NJ;++j) bff[j] = *(const bf16x8*)(Bs + (wn + j*16 + am)*32 + ak);
        #pragma unroll
        for (int i=0;i<4;++i)
            #pragma unroll
            for (int j=0;j<NJ;++j)
                acc[i][j] = __builtin_amdgcn_mfma_f32_16x16x32_bf16(af[i], bff[j], acc[i][j], 0, 0, 0);
        __syncthreads();
    }
    const int rbase = bm + wm + (lane>>4)*4;
    const int cbase = bn + wn + (lane & 15);
    #pragma unroll
    for (int i = 0; i < 4; ++i) {
        #pragma unroll
        for (int r = 0; r < 4; ++r) {
            const int row = rbase + i*16 + r;
            if (row >= M) continue;
            #pragma unroll
            for (int j = 0; j < NJ; ++j) {
                const long idx = (long)row*N + cbase + j*16;
                if (ACC) C[idx] += acc[i][j][r];
                else     C[idx]  = (CT)acc[i][j][r];
            }
        }
    }
}

// ---------------- causal depthwise conv1d (DCONV=4) + bias + silu -> bf16, x2 vectorized ----------------
__global__ void conv_silu_kernel(const bf16* __restrict__ xz, const float* __restrict__ cw,
                                 const float* __restrict__ cb, bf16* __restrict__ out)
{
    const int idx = blockIdx.x*256 + threadIdx.x;
    if (idx >= NTOK*(DI/2)) return;
    const int dp = idx % (DI/2);
    const int bl = idx / (DI/2);
    const int l  = bl % L_;
    const int di = dp*2;
    const long rowbase = (long)(bl - l)*(2*DI) + di;
    const float4 wa = *(const float4*)(cw + di*4);
    const float4 wb = *(const float4*)(cw + di*4 + 4);
    float a0 = cb[di], a1 = cb[di+1];
    #pragma unroll
    for (int k = 0; k < 4; ++k) {
        const int lt = l - 3 + k;
        if (lt >= 0) {
            const bf16x2 xv = *(const bf16x2*)(xz + rowbase + (long)lt*(2*DI));
            const float w0 = (k==0)?wa.x:(k==1)?wa.y:(k==2)?wa.z:wa.w;
            const float w1 = (k==0)?wb.x:(k==1)?wb.y:(k==2)?wb.z:wb.w;
            a0 += w0 * (float)xv[0];
            a1 += w1 * (float)xv[1];
        }
    }
    bf16x2 r;
    r[0] = (bf16)(a0 * sigmoidf_(a0));
    r[1] = (bf16)(a1 * sigmoidf_(a1));
    *(bf16x2*)(out + (long)bl*DI + di) = r;
}

// ---------------- barrier-free selective scan + D-skip + gate -> y bf16 ----------------
// block 256 = 16 di x 16 s. grid (48, B_). Whole 197-token slice in LDS (52 KB), one barrier.
// Token loop: 2 LDS reads per 2 tokens (b128 + b64); reduce via DPP (no LDS pipe).
__global__ __launch_bounds__(256)
void scan_kernel(const bf16* __restrict__ xbc, const bf16* __restrict__ comb,
                 const bf16* __restrict__ xz, const float* __restrict__ A_log,
                 const float* __restrict__ Dp, const float* __restrict__ dtb,
                 bf16* __restrict__ y)
{
    const int tid  = threadIdx.x;
    const int w    = tid >> 6, lane = tid & 63;
    const int s    = lane & 15;
    const int dlq  = lane >> 4;
    const int dl   = w*4 + dlq;
    const int bx   = blockIdx.x;
    const int cblk = (bx & 7)*6 + (bx >> 3);   // XCD-paired channel-block swizzle
    const int di0  = cblk*16;
    const int di   = di0 + dl;
    const int b    = blockIdx.y;

    const float A_s = -__expf(A_log[di*DS + s]);
    const float Dv  = Dp[di];

    __shared__ __align__(16) float2 sh_dt2[(LPAD/2)*32];  // (dt,dtx), idx2 = t2*32+2e+(t&1); 26 KB
    __shared__ __align__(16) bf16x2 sh_bc2[(LPAD/2)*32];  // (B,C) same layout; 13 KB
    __shared__ bf16x2 sh_xz[LPAD*16];                     // (x,z); 13 KB

    const long base = (long)b*L_;
    const int e = tid & 15;
    const float bias = dtb[di0 + e];
    for (int idx = tid; idx < LPAD*16; idx += 256) {
        const int t = idx >> 4;
        const int idx2 = (t >> 1)*32 + 2*e + (t & 1);
        float2 dtdx = {0.f, 0.f};
        bf16x2 bc;  bc[0] = (bf16)0.f; bc[1] = (bf16)0.f;
        bf16x2 xzv; xzv[0] = (bf16)0.f; xzv[1] = (bf16)0.f;
        if (t < L_) {
            const long row = base + t;
            const float xv = (float)xbc[row*DI + di0 + e];
            const float zv = (float)xz[row*(2*DI) + DI + di0 + e];
            const float dr = (float)comb[row*NCOMB + di0 + e] + bias;
            const float dtv = (dr > 20.f) ? dr : __logf(1.f + __expf(dr));
            dtdx.x = dtv; dtdx.y = dtv*xv;
            bc[0] = comb[row*NCOMB + 768 + e];
            bc[1] = comb[row*NCOMB + 784 + e];
            xzv[0] = (bf16)xv; xzv[1] = (bf16)zv;
        }
        sh_dt2[idx2] = dtdx;
        sh_bc2[idx2] = bc;
        sh_xz[idx]   = xzv;
    }
    __syncthreads();

    const float4* dt4 = (const float4*)sh_dt2;
    const bf16x4* bc4 = (const bf16x4*)sh_bc2;

    float h = 0.f;
    for (int c = 0; c < LPAD/16; ++c) {
        float v[16];
        #pragma unroll
        for (int t2 = 0; t2 < 8; ++t2) {
            const int g2 = c*8 + t2;
            const float4 q  = dt4[g2*16 + dl];   // dt_t0, dtx_t0, dt_t1, dtx_t1
            const bf16x4 bc = bc4[g2*16 + s];    // B_t0, C_t0, B_t1, C_t1
            const float a0 = __expf(q.x * A_s);
            h = fmaf(a0, h, q.y * (float)bc[0]);
            v[2*t2]   = h * (float)bc[1];
            const float a1 = __expf(q.z * A_s);
            h = fmaf(a1, h, q.w * (float)bc[2]);
            v[2*t2+1] = h * (float)bc[3];
        }
        rlevel_<8>(v, s); rlevel_<4>(v, s); rlevel_<2>(v, s); rlevel_<1>(v, s);
        const int gt = c*16 + s;
        if (gt < L_) {
            const bf16x2 xzv = sh_xz[gt*16 + dl];
            const float xv = (float)xzv[0], z = (float)xzv[1];
            y[(base + gt)*DI + di] = (bf16)((v[0] + Dv*xv) * z * sigmoidf_(z));
        }
    }
}

// ---------------- head bias + copy from padded GEMM output ----------------
__global__ void head_bias_kernel(const float* __restrict__ chead, const float* __restrict__ hb,
                                 float* __restrict__ out)
{
    const int idx = blockIdx.x*256 + threadIdx.x;
    if (idx >= B_*NCLS) return;
    const int n = idx % NCLS, b = idx / NCLS;
    out[idx] = chead[(long)b*1024 + n] + hb[n];
}

extern "C" void kernel_launch(void* const* d_in, const int* in_sizes, int n_in,
                              void* d_out, int out_size, void* d_ws, size_t ws_size,
                              hipStream_t stream)
{
    const float* x       = (const float*)d_in[0];
    const float* patch_w = (const float*)d_in[1];
    const float* patch_b = (const float*)d_in[2];
    const float* cls_tok = (const float*)d_in[3];
    const float* pos_emb = (const float*)d_in[4];
    const float* ln_w    = (const float*)d_in[5];
    const float* ln_b    = (const float*)d_in[6];
    const float* in_w    = (const float*)d_in[7];
    const float* conv_w  = (const float*)d_in[8];
    const float* conv_b  = (const float*)d_in[9];
    const float* xp_w    = (const float*)d_in[10];
    const float* dt_w    = (const float*)d_in[11];
    const float* dt_b    = (const float*)d_in[12];
    const float* A_log   = (const float*)d_in[13];
    const float* D_par   = (const float*)d_in[14];
    const float* out_w   = (const float*)d_in[15];
    const float* normf_w = (const float*)d_in[16];
    const float* normf_b = (const float*)d_in[17];
    const float* head_w  = (const float*)d_in[18];
    const float* head_b  = (const float*)d_in[19];
    float* out = (float*)d_out;

    // workspace layout (~111 MB)
    char* p = (char*)d_ws;
    float* tok    = (float*)p;  p += (long)NTOK*D_*4;
    bf16*  xz_b   = (bf16*)p;   p += (long)MPAD*2*DI*2;
    bf16*  xbc_b  = (bf16*)p;   p += (long)MPAD*DI*2;
    bf16*  y_b    = (bf16*)p;   p += (long)MPAD*DI*2;
    bf16*  comb_b = (bf16*)p;   p += (long)MPAD*NCOMB*2;
    bf16*  xnorm_b= (bf16*)p;   p += (long)MPAD*D_*2;
    bf16*  ln0_b  = (bf16*)p;   p += (long)64*D_*2;
    float* chead  = (float*)p;  p += (long)64*1024*4;
    bf16*  wcomb_b= (bf16*)p;   p += (long)NCOMB*DI*2;
    bf16*  w_in_b = (bf16*)p;   p += (long)DEPTH*INW_E*2;
    bf16*  w_out_b= (bf16*)p;   p += (long)DEPTH*OUTW_E*2;
    bf16*  pw_b   = (bf16*)p;   p += (long)PW_E*2;
    bf16*  hw_b   = (bf16*)p;   p += (long)HW_E*2;
    bf16*  patches = comb_b;    // pre-loop only

    const long WCONV_E = (long)DEPTH*(INW_E + OUTW_E) + PW_E + HW_E;
    wconv_all_kernel<<<dim3((WCONV_E + 255)/256), 256, 0, stream>>>(
        in_w, out_w, patch_w, head_w, w_in_b, w_out_b, pw_b, hw_b);

    im2col_kernel<<<dim3(((long)B_*196*768 + 255)/256), 256, 0, stream>>>(x, patches);
    gemm_bf16_kernel<64,0,float><<<dim3(100, 3), 256, 0, stream>>>(
        patches, pw_b, tok, NTOK, D_, 768);
    add_pos_kernel<<<dim3((NTOK*D_ + 255)/256), 256, 0, stream>>>(tok, patch_b, pos_emb, cls_tok);

    for (int layer = 0; layer < DEPTH; ++layer) {
        ln_kernel<bf16><<<dim3(NTOK/4), dim3(64,4), 0, stream>>>(
            tok, ln_w + layer*D_, ln_b + layer*D_, xnorm_b, NTOK, D_, D_);
        gemm_bf16_kernel<128,0,bf16><<<dim3(50, 12), 256, 0, stream>>>(
            xnorm_b, w_in_b + (long)layer*INW_E, xz_b, NTOK, 2*DI, D_);
        conv_silu_kernel<<<dim3((NTOK*(DI/2) + 255)/256), 256, 0, stream>>>(
            xz_b, conv_w + layer*DI*DCONV, conv_b + layer*DI, xbc_b);
        wcomb_kernel<<<dim3(NCOMB), 256, 0, stream>>>(
            dt_w + (long)layer*DI*DTR, xp_w + (long)layer*56*768, wcomb_b);
        gemm_bf16_kernel<128,0,bf16><<<dim3(50, 7), 256, 0, stream>>>(
            xbc_b, wcomb_b, comb_b, NTOK, NCOMB, DI);
        scan_kernel<<<dim3(48, B_), 256, 0, stream>>>(
            xbc_b, comb_b, xz_b, A_log + layer*DI*DS, D_par + layer*DI,
            dt_b + layer*DI, y_b);
        gemm_bf16_kernel<64,1,float><<<dim3(100, 3), 256, 0, stream>>>(
            y_b, w_out_b + (long)layer*OUTW_E, tok, NTOK, D_, DI);
    }

    ln_kernel<bf16><<<dim3(8), dim3(64,4), 0, stream>>>(tok, normf_w, normf_b, ln0_b, B_, L_*D_, D_);
    gemm_bf16_kernel<64,0,float><<<dim3(1, 8), 256, 0, stream>>>(
        ln0_b, hw_b, chead, 64, 1024, D_);
    head_bias_kernel<<<dim3((B_*NCLS + 255)/256), 256, 0, stream>>>(chead, head_b, out);
}

// Round 9
// 3142.163 us; speedup vs baseline: 1.9801x; 1.0669x over previous
//
#include <hip/hip_runtime.h>
#include <math.h>

// ---- problem dims ----
#define B_    32
#define D_    384
#define DEPTH 24
#define DI    768
#define DS    16
#define DCONV 4
#define DTR   24
#define L_    197
#define LPAD  208      // 13*16, padded token count for barrier-free scan
#define NCLS  1000
#define NTOK  (B_*L_)   // 6304
#define MPAD  6400      // padded row count for GEMM A buffers
#define NCOMB 896       // composite dt|B|C GEMM width (768 dt + 16 B + 16 C + 96 pad)

typedef __bf16 bf16;
typedef __bf16 bf16x2 __attribute__((ext_vector_type(2)));
typedef __bf16 bf16x4 __attribute__((ext_vector_type(4)));
typedef __bf16 bf16x8 __attribute__((ext_vector_type(8)));
typedef float  floatx4 __attribute__((ext_vector_type(4)));

#define INW_E  (1536*384)
#define OUTW_E (384*768)
#define PW_E   (384*768)
#define HW_E   (1024*384)

__device__ __forceinline__ float sigmoidf_(float x){ return 1.f/(1.f+__expf(-x)); }

// DPP-based lane exchange within 16-lane rows (keeps the LDS pipe free)
template<int CTRL>
__device__ __forceinline__ float dppf_(float x){
    return __int_as_float(__builtin_amdgcn_update_dpp(0, __float_as_int(x), CTRL, 0xF, 0xF, true));
}
template<int M>
__device__ __forceinline__ float sxor_(float x){
    if constexpr (M==1)      return dppf_<0xB1>(x);               // quad_perm [1,0,3,2]
    else if constexpr (M==2) return dppf_<0x4E>(x);               // quad_perm [2,3,0,1]
    else if constexpr (M==4) return dppf_<0x1B>(dppf_<0x141>(x)); // xor7 then xor3 = xor4
    else                     return dppf_<0x128>(x);              // row_ror:8 = xor8 (row=16)
}
template<int M>
__device__ __forceinline__ void rlevel_(float* v, const int s){
    const bool hi = (s & M) != 0;
    #pragma unroll
    for (int i = 0; i < M; ++i) {
        const float keep = hi ? v[i+M] : v[i];
        const float send = hi ? v[i] : v[i+M];
        v[i] = keep + sxor_<M>(send);
    }
}

// ---------------- all-weights fp32 -> bf16 conversion, 8 elems/thread ----------------
#define INW_ALL  ((long)DEPTH*INW_E)
#define OUTW_ALL ((long)DEPTH*OUTW_E)
#define WCONV_TOT (INW_ALL + OUTW_ALL + PW_E + HW_E)
__global__ void wconv_all_kernel(const float* __restrict__ in_w, const float* __restrict__ out_w,
                                 const float* __restrict__ patch_w, const float* __restrict__ head_w,
                                 bf16* __restrict__ w_in_b, bf16* __restrict__ w_out_b,
                                 bf16* __restrict__ pw_b, bf16* __restrict__ hw_b)
{
    long idx = ((long)blockIdx.x*256 + threadIdx.x)*8;
    if (idx >= WCONV_TOT) return;
    const float* src; bf16* dst; long off;
    bool pad = false;
    if (idx < INW_ALL)                { src = in_w;  dst = w_in_b;  off = idx; }
    else if (idx < INW_ALL+OUTW_ALL)  { src = out_w; dst = w_out_b; off = idx - INW_ALL; }
    else if (idx < INW_ALL+OUTW_ALL+PW_E) { src = patch_w; dst = pw_b; off = idx - INW_ALL - OUTW_ALL; }
    else { off = idx - INW_ALL - OUTW_ALL - PW_E; src = head_w; dst = hw_b; pad = (off >= (long)NCLS*384); }
    bf16x8 r;
    if (pad) {
        #pragma unroll
        for (int j = 0; j < 8; ++j) r[j] = (bf16)0.f;
    } else {
        const float4 a = *(const float4*)(src + off);
        const float4 c = *(const float4*)(src + off + 4);
        r[0]=(bf16)a.x; r[1]=(bf16)a.y; r[2]=(bf16)a.z; r[3]=(bf16)a.w;
        r[4]=(bf16)c.x; r[5]=(bf16)c.y; r[6]=(bf16)c.z; r[7]=(bf16)c.w;
    }
    *(bf16x8*)(dst + off) = r;
}

// ---------------- merged: layernorm (blocks 0..1575) + wcomb (blocks 1576..2471) ----------------
// ln: one wave per row over last dim 384.  wcomb: composite dt|B|C weight rows.
__global__ void ln_wcomb_kernel(const float* __restrict__ x, const float* __restrict__ w,
                                const float* __restrict__ b, bf16* __restrict__ out,
                                const float* __restrict__ dtw, const float* __restrict__ xpw,
                                bf16* __restrict__ wc)
{
    if (blockIdx.x < NTOK/4) {
        const int row = blockIdx.x*4 + threadIdx.y;
        const int lane = threadIdx.x;
        const float* xr = x + (long)row*D_;
        float v[6]; float s = 0.f;
        #pragma unroll
        for (int i = 0; i < 6; ++i) { v[i] = xr[lane + 64*i]; s += v[i]; }
        #pragma unroll
        for (int o = 32; o; o >>= 1) s += __shfl_xor(s, o, 64);
        const float mu = s * (1.f/384.f);
        float var = 0.f;
        #pragma unroll
        for (int i = 0; i < 6; ++i) { float d = v[i]-mu; var += d*d; }
        #pragma unroll
        for (int o = 32; o; o >>= 1) var += __shfl_xor(var, o, 64);
        const float rstd = rsqrtf(var*(1.f/384.f) + 1e-5f);
        bf16* orow = out + (long)row*D_;
        #pragma unroll
        for (int i = 0; i < 6; ++i) { int c = lane + 64*i; orow[c] = (bf16)((v[i]-mu)*rstd*w[c] + b[c]); }
    } else {
        const int o = blockIdx.x - NTOK/4;
        const int tid = threadIdx.y*64 + threadIdx.x;
        if (o < 768) {
            __shared__ float sw[24];
            if (tid < 24) sw[tid] = dtw[(long)o*DTR + tid];
            __syncthreads();
            for (int i = tid; i < DI; i += 256) {
                float acc = 0.f;
                #pragma unroll
                for (int r = 0; r < 24; ++r) acc += sw[r]*xpw[r*DI + i];
                wc[(long)o*DI + i] = (bf16)acc;
            }
        } else if (o < 800) {
            const float* src = xpw + (long)(o - 768 + 24)*DI;
            for (int i = tid; i < DI; i += 256) wc[(long)o*DI + i] = (bf16)src[i];
        } else {
            for (int i = tid; i < DI; i += 256) wc[(long)o*DI + i] = (bf16)0.f;
        }
    }
}

// ---------------- im2col: x[B,3,224,224] -> patches[b*197+1+pi, 768] bf16 ----------------
__global__ void im2col_kernel(const float* __restrict__ x, bf16* __restrict__ patches)
{
    const long idx = (long)blockIdx.x*256 + threadIdx.x;
    if (idx >= (long)B_*196*768) return;
    const int k = idx % 768;
    const int prow = idx / 768;
    const int b = prow / 196, pi = prow % 196;
    const int ph = pi / 14, pw = pi % 14;
    const int c = k >> 8, rem = k & 255, ii = rem >> 4, jj = rem & 15;
    patches[((long)(b*L_ + 1 + pi))*768 + k] =
        (bf16)x[(((long)b*3 + c)*224 + ph*16 + ii)*224 + pw*16 + jj];
}

// ---------------- tok = feat + pb + pos ; cls row = cls + pos ----------------
__global__ void add_pos_kernel(float* __restrict__ tok, const float* __restrict__ pb,
                               const float* __restrict__ pos, const float* __restrict__ cls)
{
    const int idx = blockIdx.x*256 + threadIdx.x;
    if (idx >= NTOK*D_) return;
    const int dd = idx % D_;
    const int row = idx / D_;
    const int p = row % L_;
    if (p == 0) tok[idx] = cls[dd] + pos[dd];
    else        tok[idx] += pb[dd] + pos[p*D_ + dd];
}

// ---------------- layernorm (standalone, used for final norm) ----------------
template<typename OUT_T>
__global__ void ln_kernel(const float* __restrict__ x, const float* __restrict__ w,
                          const float* __restrict__ b, OUT_T* __restrict__ out,
                          int rows, int xstride, int ostride)
{
    const int row = blockIdx.x*blockDim.y + threadIdx.y;
    if (row >= rows) return;
    const int lane = threadIdx.x;
    const float* xr = x + (long)row*xstride;
    float v[6]; float s = 0.f;
    #pragma unroll
    for (int i = 0; i < 6; ++i) { v[i] = xr[lane + 64*i]; s += v[i]; }
    #pragma unroll
    for (int o = 32; o; o >>= 1) s += __shfl_xor(s, o, 64);
    const float mu = s * (1.f/384.f);
    float var = 0.f;
    #pragma unroll
    for (int i = 0; i < 6; ++i) { float d = v[i]-mu; var += d*d; }
    #pragma unroll
    for (int o = 32; o; o >>= 1) var += __shfl_xor(var, o, 64);
    const float rstd = rsqrtf(var*(1.f/384.f) + 1e-5f);
    OUT_T* orow = out + (long)row*ostride;
    #pragma unroll
    for (int i = 0; i < 6; ++i) { int c = lane + 64*i; orow[c] = (OUT_T)((v[i]-mu)*rstd*w[c] + b[c]); }
}

// ---------------- bf16 MFMA GEMM:  C[m,n] (+)= A[m,:K] . B[n,:K]  (B stored [N][K]) ----------------
template<int BM, int ACC, typename CT>
__global__ __launch_bounds__(256)
void gemm_bf16_kernel(const bf16* __restrict__ A, const bf16* __restrict__ B,
                      CT* __restrict__ C, int M, int N, int K)
{
    constexpr int ASLABS = BM/16;
    constexpr int NJ = (BM == 128) ? 4 : 2;
    __shared__ bf16 As[BM*32];
    __shared__ bf16 Bs[128*32];
    const int tid  = threadIdx.x;
    const int wave = tid >> 6, lane = tid & 63;
    const int bm = blockIdx.x*BM, bn = blockIdx.y*128;
    const int wm = (BM == 128) ? (wave>>1)*64 : 0;
    const int wn = (BM == 128) ? (wave&1)*64 : wave*32;
    floatx4 acc[4][NJ];
    #pragma unroll
    for (int i=0;i<4;++i)
        #pragma unroll
        for (int j=0;j<NJ;++j) acc[i][j] = (floatx4){0.f,0.f,0.f,0.f};

    const int lrow = lane >> 2;
    const int lcol = (lane & 3) * 8;
    const int am = lane & 15, ak = (lane>>4)*8;

    for (int k0 = 0; k0 < K; k0 += 32) {
        #pragma unroll
        for (int s = wave; s < ASLABS + 8; s += 4) {
            if (s < ASLABS) {
                const bf16* ga = A + (long)(bm + s*16 + lrow)*K + k0 + lcol;
                __builtin_amdgcn_global_load_lds(
                    (const __attribute__((address_space(1))) void*)ga,
                    (__attribute__((address_space(3))) void*)(As + s*512), 16, 0, 0);
            } else {
                const int s2 = s - ASLABS;
                const bf16* gb = B + (long)(bn + s2*16 + lrow)*K + k0 + lcol;
                __builtin_amdgcn_global_load_lds(
                    (const __attribute__((address_space(1))) void*)gb,
                    (__attribute__((address_space(3))) void*)(Bs + s2*512), 16, 0, 0);
            }
        }
        __syncthreads();
        bf16x8 af[4], bff[NJ];
        #pragma unroll
        for (int i=0;i<4;++i) af[i]  = *(const bf16x8*)(As + (wm + i*16 + am)*32 + ak);
        #pragma unroll
        for (int j=0;j<NJ;++j) bff[j] = *(const bf16x8*)(Bs + (wn + j*16 + am)*32 + ak);
        #pragma unroll
        for (int i=0;i<4;++i)
            #pragma unroll
            for (int j=0;j<NJ;++j)
                acc[i][j] = __builtin_amdgcn_mfma_f32_16x16x32_bf16(af[i], bff[j], acc[i][j], 0, 0, 0);
        __syncthreads();
    }
    const int rbase = bm + wm + (lane>>4)*4;
    const int cbase = bn + wn + (lane & 15);
    #pragma unroll
    for (int i = 0; i < 4; ++i) {
        #pragma unroll
        for (int r = 0; r < 4; ++r) {
            const int row = rbase + i*16 + r;
            if (row >= M) continue;
            #pragma unroll
            for (int j = 0; j < NJ; ++j) {
                const long idx = (long)row*N + cbase + j*16;
                if (ACC) C[idx] += acc[i][j][r];
                else     C[idx]  = (CT)acc[i][j][r];
            }
        }
    }
}

// ---------------- causal depthwise conv1d (DCONV=4) + bias + silu -> bf16, x8 vectorized ----------------
__global__ void conv_silu_kernel(const bf16* __restrict__ xz, const float* __restrict__ cw,
                                 const float* __restrict__ cb, bf16* __restrict__ out)
{
    const int idx = blockIdx.x*256 + threadIdx.x;      // over NTOK*96
    if (idx >= NTOK*96) return;
    const int g  = idx % 96;
    const int bl = idx / 96;
    const int l  = bl % L_;
    const int di = g*8;
    const long rowbase = (long)(bl - l)*(2*DI) + di;
    bf16x8 xv[4];
    #pragma unroll
    for (int k = 0; k < 4; ++k) {
        const int lt = l - 3 + k;
        if (lt >= 0) {
            xv[k] = *(const bf16x8*)(xz + rowbase + (long)lt*(2*DI));
        } else {
            #pragma unroll
            for (int j = 0; j < 8; ++j) xv[k][j] = (bf16)0.f;
        }
    }
    bf16x8 r;
    #pragma unroll
    for (int j = 0; j < 8; ++j) {
        const float4 wj = ((const float4*)cw)[di + j];
        float a = cb[di + j];
        a += wj.x*(float)xv[0][j] + wj.y*(float)xv[1][j] + wj.z*(float)xv[2][j] + wj.w*(float)xv[3][j];
        r[j] = (bf16)(a * sigmoidf_(a));
    }
    *(bf16x8*)(out + (long)bl*DI + di) = r;
}

// ---------------- barrier-free selective scan + D-skip + gate -> y bf16 ----------------
// block 256 = 16 di x 16 s. grid (48, B_). Whole 197-token slice in LDS (39 KB -> 4 blocks/CU),
// one barrier. Token loop: 2 ds_read_b64 per 2 tokens; reduce via DPP.
__global__ __launch_bounds__(256)
void scan_kernel(const bf16* __restrict__ xbc, const bf16* __restrict__ comb,
                 const bf16* __restrict__ xz, const float* __restrict__ A_log,
                 const float* __restrict__ Dp, const float* __restrict__ dtb,
                 bf16* __restrict__ y)
{
    const int tid  = threadIdx.x;
    const int w    = tid >> 6, lane = tid & 63;
    const int s    = lane & 15;
    const int dlq  = lane >> 4;
    const int dl   = w*4 + dlq;
    const int bx   = blockIdx.x;
    const int cblk = (bx & 7)*6 + (bx >> 3);   // XCD-paired channel-block swizzle
    const int di0  = cblk*16;
    const int di   = di0 + dl;
    const int b    = blockIdx.y;

    const float A2_s = -__expf(A_log[di*DS + s]) * 1.44269504f;  // fold log2e -> exp2
    const float Dv   = Dp[di];

    __shared__ __align__(16) bf16x2 sh_dt2[(LPAD/2)*32];  // (dt,dtx) pair-interleaved; 13 KB
    __shared__ __align__(16) bf16x2 sh_bc2[(LPAD/2)*32];  // (B,C) pair-interleaved;  13 KB
    __shared__ bf16x2 sh_xz[LPAD*16];                     // (x,z);                  13 KB

    const long base = (long)b*L_;
    const int e = tid & 15;
    const float bias = dtb[di0 + e];
    for (int idx = tid; idx < LPAD*16; idx += 256) {
        const int t = idx >> 4;
        const int idx2 = (t >> 1)*32 + 2*e + (t & 1);
        bf16x2 dtdx; dtdx[0] = (bf16)0.f; dtdx[1] = (bf16)0.f;
        bf16x2 bc;   bc[0] = (bf16)0.f;   bc[1] = (bf16)0.f;
        bf16x2 xzv;  xzv[0] = (bf16)0.f;  xzv[1] = (bf16)0.f;
        if (t < L_) {
            const long row = base + t;
            const float xv = (float)xbc[row*DI + di0 + e];
            const float zv = (float)xz[row*(2*DI) + DI + di0 + e];
            const float dr = (float)comb[row*NCOMB + di0 + e] + bias;
            const float dtv = (dr > 20.f) ? dr : __logf(1.f + __expf(dr));
            dtdx[0] = (bf16)dtv; dtdx[1] = (bf16)(dtv*xv);
            bc[0] = comb[row*NCOMB + 768 + e];
            bc[1] = comb[row*NCOMB + 784 + e];
            xzv[0] = (bf16)xv; xzv[1] = (bf16)zv;
        }
        sh_dt2[idx2] = dtdx;
        sh_bc2[idx2] = bc;
        sh_xz[idx]   = xzv;
    }
    __syncthreads();

    const bf16x4* dt4 = (const bf16x4*)sh_dt2;
    const bf16x4* bc4 = (const bf16x4*)sh_bc2;

    float h = 0.f;
    for (int c = 0; c < LPAD/16; ++c) {
        float v[16];
        #pragma unroll
        for (int t2 = 0; t2 < 8; ++t2) {
            const int g2 = c*8 + t2;
            const bf16x4 q  = dt4[g2*16 + dl];   // dt_t0, dtx_t0, dt_t1, dtx_t1
            const bf16x4 bc = bc4[g2*16 + s];    // B_t0, C_t0, B_t1, C_t1
            const float a0 = __builtin_amdgcn_exp2f((float)q[0] * A2_s);
            h = fmaf(a0, h, (float)q[1] * (float)bc[0]);
            v[2*t2]   = h * (float)bc[1];
            const float a1 = __builtin_amdgcn_exp2f((float)q[2] * A2_s);
            h = fmaf(a1, h, (float)q[3] * (float)bc[2]);
            v[2*t2+1] = h * (float)bc[3];
        }
        rlevel_<8>(v, s); rlevel_<4>(v, s); rlevel_<2>(v, s); rlevel_<1>(v, s);
        const int gt = c*16 + s;
        if (gt < L_) {
            const bf16x2 xzv = sh_xz[gt*16 + dl];
            const float xv = (float)xzv[0], z = (float)xzv[1];
            y[(base + gt)*DI + di] = (bf16)((v[0] + Dv*xv) * z * sigmoidf_(z));
        }
    }
}

// ---------------- head bias + copy from padded GEMM output ----------------
__global__ void head_bias_kernel(const float* __restrict__ chead, const float* __restrict__ hb,
                                 float* __restrict__ out)
{
    const int idx = blockIdx.x*256 + threadIdx.x;
    if (idx >= B_*NCLS) return;
    const int n = idx % NCLS, b = idx / NCLS;
    out[idx] = chead[(long)b*1024 + n] + hb[n];
}

extern "C" void kernel_launch(void* const* d_in, const int* in_sizes, int n_in,
                              void* d_out, int out_size, void* d_ws, size_t ws_size,
                              hipStream_t stream)
{
    const float* x       = (const float*)d_in[0];
    const float* patch_w = (const float*)d_in[1];
    const float* patch_b = (const float*)d_in[2];
    const float* cls_tok = (const float*)d_in[3];
    const float* pos_emb = (const float*)d_in[4];
    const float* ln_w    = (const float*)d_in[5];
    const float* ln_b    = (const float*)d_in[6];
    const float* in_w    = (const float*)d_in[7];
    const float* conv_w  = (const float*)d_in[8];
    const float* conv_b  = (const float*)d_in[9];
    const float* xp_w    = (const float*)d_in[10];
    const float* dt_w    = (const float*)d_in[11];
    const float* dt_b    = (const float*)d_in[12];
    const float* A_log   = (const float*)d_in[13];
    const float* D_par   = (const float*)d_in[14];
    const float* out_w   = (const float*)d_in[15];
    const float* normf_w = (const float*)d_in[16];
    const float* normf_b = (const float*)d_in[17];
    const float* head_w  = (const float*)d_in[18];
    const float* head_b  = (const float*)d_in[19];
    float* out = (float*)d_out;

    // workspace layout (~111 MB)
    char* p = (char*)d_ws;
    float* tok    = (float*)p;  p += (long)NTOK*D_*4;
    bf16*  xz_b   = (bf16*)p;   p += (long)MPAD*2*DI*2;
    bf16*  xbc_b  = (bf16*)p;   p += (long)MPAD*DI*2;
    bf16*  y_b    = (bf16*)p;   p += (long)MPAD*DI*2;
    bf16*  comb_b = (bf16*)p;   p += (long)MPAD*NCOMB*2;
    bf16*  xnorm_b= (bf16*)p;   p += (long)MPAD*D_*2;
    bf16*  ln0_b  = (bf16*)p;   p += (long)64*D_*2;
    float* chead  = (float*)p;  p += (long)64*1024*4;
    bf16*  wcomb_b= (bf16*)p;   p += (long)NCOMB*DI*2;
    bf16*  w_in_b = (bf16*)p;   p += (long)DEPTH*INW_E*2;
    bf16*  w_out_b= (bf16*)p;   p += (long)DEPTH*OUTW_E*2;
    bf16*  pw_b   = (bf16*)p;   p += (long)PW_E*2;
    bf16*  hw_b   = (bf16*)p;   p += (long)HW_E*2;
    bf16*  patches = comb_b;    // pre-loop only

    wconv_all_kernel<<<dim3((WCONV_TOT/8 + 255)/256), 256, 0, stream>>>(
        in_w, out_w, patch_w, head_w, w_in_b, w_out_b, pw_b, hw_b);

    im2col_kernel<<<dim3(((long)B_*196*768 + 255)/256), 256, 0, stream>>>(x, patches);
    gemm_bf16_kernel<64,0,float><<<dim3(100, 3), 256, 0, stream>>>(
        patches, pw_b, tok, NTOK, D_, 768);
    add_pos_kernel<<<dim3((NTOK*D_ + 255)/256), 256, 0, stream>>>(tok, patch_b, pos_emb, cls_tok);

    for (int layer = 0; layer < DEPTH; ++layer) {
        ln_wcomb_kernel<<<dim3(NTOK/4 + NCOMB), dim3(64,4), 0, stream>>>(
            tok, ln_w + layer*D_, ln_b + layer*D_, xnorm_b,
            dt_w + (long)layer*DI*DTR, xp_w + (long)layer*56*768, wcomb_b);
        gemm_bf16_kernel<128,0,bf16><<<dim3(50, 12), 256, 0, stream>>>(
            xnorm_b, w_in_b + (long)layer*INW_E, xz_b, NTOK, 2*DI, D_);
        conv_silu_kernel<<<dim3((NTOK*96 + 255)/256), 256, 0, stream>>>(
            xz_b, conv_w + layer*DI*DCONV, conv_b + layer*DI, xbc_b);
        gemm_bf16_kernel<128,0,bf16><<<dim3(50, 7), 256, 0, stream>>>(
            xbc_b, wcomb_b, comb_b, NTOK, NCOMB, DI);
        scan_kernel<<<dim3(48, B_), 256, 0, stream>>>(
            xbc_b, comb_b, xz_b, A_log + layer*DI*DS, D_par + layer*DI,
            dt_b + layer*DI, y_b);
        gemm_bf16_kernel<64,1,float><<<dim3(100, 3), 256, 0, stream>>>(
            y_b, w_out_b + (long)layer*OUTW_E, tok, NTOK, D_, DI);
    }

    ln_kernel<bf16><<<dim3(8), dim3(64,4), 0, stream>>>(tok, normf_w, normf_b, ln0_b, B_, L_*D_, D_);
    gemm_bf16_kernel<64,0,float><<<dim3(1, 8), 256, 0, stream>>>(
        ln0_b, hw_b, chead, 64, 1024, D_);
    head_bias_kernel<<<dim3((B_*NCLS + 255)/256), 256, 0, stream>>>(chead, head_b, out);
}